// Round 15
// baseline (616.904 us; speedup 1.0000x reference)
//
#include <hip/hip_runtime.h>

#define L 2048
#define D 2048
#define NH 16
#define HD 128

typedef __attribute__((ext_vector_type(8))) _Float16 half8;
typedef __attribute__((ext_vector_type(4))) float f32x4;

__device__ __forceinline__ void gload_lds16(const void* g, void* l) {
    __builtin_amdgcn_global_load_lds(
        (const __attribute__((address_space(1))) uint32_t*)g,
        (__attribute__((address_space(3))) uint32_t*)l, 16, 0, 0);
}

// pack two f32 -> fp16x2 (RTZ), return as u32
__device__ __forceinline__ unsigned pkrtz_u32(float a, float b) {
    union { __fp16 __attribute__((ext_vector_type(2))) h; unsigned u; } c;
    c.h = __builtin_amdgcn_cvt_pkrtz(a, b);
    return c.u;
}

// ---------------- fused f32 -> fp16 convert of x, W_qkv, W_out ----------------
__global__ void cvt3_kernel(const float* __restrict__ a, const float* __restrict__ b,
                            const float* __restrict__ c, _Float16* __restrict__ oa,
                            _Float16* __restrict__ ob, _Float16* __restrict__ oc,
                            int na, int nb, int nc) {
    int idx = blockIdx.x * blockDim.x + threadIdx.x;
    int stride = gridDim.x * blockDim.x;
    int ntot = na + nb + nc;
    for (int i = idx; i < ntot; i += stride) {
        const float* src; _Float16* dst; int j;
        if (i < na)            { src = a; dst = oa; j = i; }
        else if (i < na + nb)  { src = b; dst = ob; j = i - na; }
        else                   { src = c; dst = oc; j = i - na - nb; }
        float4 v = reinterpret_cast<const float4*>(src)[j];
        union { _Float16 h[4]; uint2 u; } pk;
        pk.h[0] = (_Float16)v.x; pk.h[1] = (_Float16)v.y;
        pk.h[2] = (_Float16)v.z; pk.h[3] = (_Float16)v.w;
        reinterpret_cast<uint2*>(dst)[j] = pk.u;
    }
}

// ---------------- NT GEMM: C[M][N] = A[M][K] * B[N][K]^T ----------------
// Main loop: r13-exact proven structure (2-buffer, stage(t+1) -> compute(t) ->
// vmcnt(0)+__syncthreads drain). r14's triple-buffer/counted-vmcnt variant was
// SLOWER (73->82us) -- consistent with guide m99/m131-m140: the compiler
// already schedules this structure near its ceiling. T1 XCD swizzle kept
// (FETCH 102->45MB, halved).
// EPI 0: q/k col-tiles (one full head-plane [128 l][128 d] per block) get a
//        FUSED RMSNorm+RoPE epilogue (norm_rope kernel deleted):
//        - row sum-of-squares: in-lane over j, 16-lane shfl_xor tree, 1KB LDS
//          exchange between the two wc-half waves (block-uniform barrier);
//        - RoPE pair (d, d^1) = adjacent lanes -> shfl_xor(nv, 1);
//        - rope on NATURAL d, then store: q linear, k with d^((l&7)<<3).
//        v -> vt[h][d][l^((d&7)<<3)] (pre-swizzled for attn V staging).
// EPI 1: write f32 C row-major to Cout.
template <int EPI>
__global__ __launch_bounds__(256) void gemm_nt(
    const _Float16* __restrict__ A, const _Float16* __restrict__ B,
    float* __restrict__ Cout, _Float16* __restrict__ qk, _Float16* __restrict__ vt,
    int M, int N, int K)
{
    __shared__ __align__(16) _Float16 Asm[2][128 * 32];   // 2 x 8 KB
    __shared__ __align__(16) _Float16 Bsm[2][128 * 32];   // 2 x 8 KB
    int tid = threadIdx.x;
    int wid = tid >> 6;
    int lane = tid & 63;
    int wr = wid >> 1, wc = wid & 1;

    // T1: XCD-aware block swizzle (nwg divisible by 8 for both launches)
    int nwg = gridDim.x * gridDim.y;
    int bid = blockIdx.y * gridDim.x + blockIdx.x;
    int qch = nwg >> 3;
    int swz = (bid & 7) * qch + (bid >> 3);
    int bx = swz % gridDim.x;
    int by = swz / gridDim.x;
    int m0 = bx * 128;
    int n0 = by * 128;
    int lr = lane & 15;   // row/col within 16
    int lg = lane >> 4;   // group 0..3

    // staging source: thread tid covers tile rows {tid>>2, 64+(tid>>2)}, byte col (tid&3)*16
    const char* Asrc = (const char*)(A + (size_t)(m0 + (tid >> 2)) * K) + (tid & 3) * 16;
    const char* Bsrc = (const char*)(B + (size_t)(n0 + (tid >> 2)) * K) + (tid & 3) * 16;
    size_t rowskip = (size_t)64 * K * 2;   // 64 rows of source, bytes

    auto stage = [&](int k0, int b) {
        const char* as = Asrc + (size_t)k0 * 2;
        const char* bs = Bsrc + (size_t)k0 * 2;
        char* ad = (char*)&Asm[b][0] + wid * 1024;   // + lane*16 by hardware
        char* bd = (char*)&Bsm[b][0] + wid * 1024;
        gload_lds16(as, ad);
        gload_lds16(as + rowskip, ad + 4096);
        gload_lds16(bs, bd);
        gload_lds16(bs + rowskip, bd + 4096);
    };

    f32x4 acc[4][4];
#pragma unroll
    for (int i = 0; i < 4; i++)
#pragma unroll
        for (int j = 0; j < 4; j++)
            acc[i][j] = (f32x4){0.f, 0.f, 0.f, 0.f};

    int NT = K / 32;
    stage(0, 0);
    asm volatile("s_waitcnt vmcnt(0)" ::: "memory");
    __syncthreads();

    for (int t = 0; t < NT; t++) {
        int cur = t & 1;
        if (t + 1 < NT) stage((t + 1) * 32, cur ^ 1);

        const char* ab = (const char*)&Asm[cur][0] + (wr * 64 + lr) * 64 + lg * 16;
        const char* bb = (const char*)&Bsm[cur][0] + (wc * 64 + lr) * 64 + lg * 16;
        half8 a[4], b[4];
#pragma unroll
        for (int i = 0; i < 4; i++) a[i] = *(const half8*)(ab + i * 1024);
#pragma unroll
        for (int j = 0; j < 4; j++) b[j] = *(const half8*)(bb + j * 1024);
#pragma unroll
        for (int i = 0; i < 4; i++)
#pragma unroll
            for (int j = 0; j < 4; j++)
                acc[i][j] = __builtin_amdgcn_mfma_f32_16x16x32_f16(a[i], b[j], acc[i][j], 0, 0, 0);

        asm volatile("s_waitcnt vmcnt(0)" ::: "memory");
        __syncthreads();
    }

    if (EPI == 0 && (n0 >> 11) < 2) {
        // ---- fused RMSNorm + RoPE epilogue (q/k head-plane tile) ----
        int tsel = n0 >> 11;
        int hh = (n0 & 2047) >> 7;
        float* red = (float*)&Asm[0][0];   // reuse LDS: [128 rows][2 wc] f32 = 1KB

        // per-row sum of squares over this wave's 64 cols
        float ss[4][4];
#pragma unroll
        for (int i = 0; i < 4; i++)
#pragma unroll
            for (int r = 0; r < 4; r++) {
                float s = 0.f;
#pragma unroll
                for (int j = 0; j < 4; j++) s += acc[i][j][r] * acc[i][j][r];
                ss[i][r] = s;
            }
#pragma unroll
        for (int off = 1; off < 16; off <<= 1)
#pragma unroll
            for (int i = 0; i < 4; i++)
#pragma unroll
                for (int r = 0; r < 4; r++)
                    ss[i][r] += __shfl_xor(ss[i][r], off);
        if (lr == 0) {
#pragma unroll
            for (int i = 0; i < 4; i++)
#pragma unroll
                for (int r = 0; r < 4; r++)
                    red[(wr * 64 + i * 16 + lg * 4 + r) * 2 + wc] = ss[i][r];
        }
        __syncthreads();   // block-uniform branch: all threads reach this

        float rsq[4][4];
#pragma unroll
        for (int i = 0; i < 4; i++)
#pragma unroll
            for (int r = 0; r < 4; r++) {
                int rw = wr * 64 + i * 16 + lg * 4 + r;
                float s2 = red[rw * 2] + red[rw * 2 + 1];
                rsq[i][r] = rsqrtf(s2 * (1.0f / 128.0f) + 1e-5f);
            }

        // rope frequencies: pair p = d>>1, freq = base^(-2p/128)
        float freqj[4];
#pragma unroll
        for (int j = 0; j < 4; j++) {
            int p = (wc * 64 + j * 16 + lr) >> 1;
            freqj[j] = expf(-0.17988946f * (float)p);   // 2*ln(1e5)/128
        }
        bool oddl = lr & 1;
#pragma unroll
        for (int i = 0; i < 4; i++)
#pragma unroll
            for (int j = 0; j < 4; j++)
#pragma unroll
                for (int r = 0; r < 4; r++) {
                    float nv = acc[i][j][r] * rsq[i][r];
                    float pv = __shfl_xor(nv, 1);   // partner d^1 (lane lr^1)
                    int l = m0 + wr * 64 + i * 16 + lg * 4 + r;
                    float sc, cc;
                    sincosf((float)l * freqj[j], &sc, &cc);
                    // out[2p] = t_odd*c - t_even*s ; out[2p+1] = t_odd*s + t_even*c
                    float outv = oddl ? (nv * sc + pv * cc) : (pv * cc - nv * sc);
                    int d = wc * 64 + j * 16 + lr;
                    if (tsel == 0) {
                        qk[(((size_t)hh) * L + l) * HD + d] = (_Float16)outv;
                    } else {
                        int dsw = d ^ ((l & 7) << 3);   // pre-swizzle for attn K staging
                        qk[(((size_t)NH + hh) * L + l) * HD + dsw] = (_Float16)outv;
                    }
                }
    } else {
#pragma unroll
        for (int i = 0; i < 4; i++) {
#pragma unroll
            for (int j = 0; j < 4; j++) {
#pragma unroll
                for (int r = 0; r < 4; r++) {
                    int row = m0 + wr * 64 + i * 16 + lg * 4 + r;  // C layout
                    int col = n0 + wc * 64 + j * 16 + lr;
                    float v = acc[i][j][r];
                    if (EPI == 0) {
                        int w2 = col & 2047;
                        int h = w2 >> 7, d = w2 & 127;
                        int lsw = row ^ ((d & 7) << 3);   // pre-swizzle for attn V staging
                        vt[((size_t)h * HD + d) * L + lsw] = (_Float16)v;
                    } else {
                        Cout[(size_t)row * N + col] = v;
                    }
                }
            }
        }
    }
}

// ---------------- causal flash attention, v11: V via LDS ----------------
// (unchanged from r13 -- K+V staged in LDS, swapped QK^T, in-register P,
// counted vmcnt + raw barrier, dynamic work queue, half partials)
__global__ __launch_bounds__(256, 3) void attn_kernel(
    const _Float16* __restrict__ qk, const _Float16* __restrict__ vt,
    _Float16* __restrict__ Oab, float* __restrict__ Lab, int* __restrict__ cnt)
{
    __shared__ __align__(16) _Float16 Kt[2][64 * HD];     // 2 x 16 KB
    __shared__ __align__(16) _Float16 Vt[64 * HD];        // 16 KB, single-buffered
    __shared__ int sh_i;
    int wid = threadIdx.x >> 6, lane = threadIdx.x & 63;
    int lr = lane & 15, lg = lane >> 4;

    const float scale = 0.08838834764831845f;  // 1/sqrt(128)
    const float OFF = 4.0f;                    // static exp offset (absolute)

    for (;;) {
        __syncthreads();   // full drain between items (protects sh_i + Kt/Vt reuse)
        if (threadIdx.x == 0) sh_i = atomicAdd(cnt, 1);
        __syncthreads();
        int item = sh_i;
        if (item >= 1024) return;

        // decode big-first: qt descending; 32 items (16h x 2half) per qt
        int qt = 31 - (item >> 5);
        int h = (item >> 1) & 15;
        int half = item & 1;
        int n = qt + 1;
        int mid = (n + 1) >> 1;
        int t0 = half ? mid : 0;
        int t1 = half ? n : mid;
        int q0 = qt * 64 + wid * 16;
        int q_abs = q0 + lr;               // this lane's q-row (swapped layout)

        const _Float16* qn = qk + (size_t)h * L * HD;              // q plane
        const _Float16* kn = qk + ((size_t)(NH + h) * L) * HD;     // k plane (swizzled)
        const _Float16* vp = vt + (size_t)h * HD * L;              // v^T plane (swizzled)

        half8 qa[4];
#pragma unroll
        for (int kk = 0; kk < 4; kk++)
            qa[kk] = *reinterpret_cast<const half8*>(qn + (size_t)(q0 + lr) * HD + kk * 32 + lg * 8);

        f32x4 oacc[8];
#pragma unroll
        for (int jo = 0; jo < 8; jo++) oacc[jo] = (f32x4){0.f, 0.f, 0.f, 0.f};
        float lsum = 0.f;                  // per-lane scalar (q-row lr, this lane's kv slice)

        // per-wave QUARTER K stage: wave w copies kv rows 16w..16w+15 (4 KB, 4 DMAs)
        auto stage_k = [&](int t, int b) {
            const char* src = (const char*)(kn + (size_t)t * 64 * HD) + wid * 4096 + lane * 16;
            char* dst = (char*)&Kt[b][0] + wid * 4096;
#pragma unroll
            for (int i = 0; i < 4; i++)
                gload_lds16(src + i * 1024, dst + i * 1024);
        };
        // per-wave QUARTER V stage: tile [128 d][64 kv], 128B per d-row.
        auto stage_v = [&](int t) {
            const char* vpb = (const char*)vp + (size_t)t * 128;   // kv0*2 bytes
            char* dst = (char*)&Vt[0] + wid * 4096;
            int dbase = wid * 32 + (lane >> 3);
            int colb = (lane & 7) * 16;
#pragma unroll
            for (int i = 0; i < 4; i++)
                gload_lds16(vpb + (size_t)(dbase + i * 8) * (L * 2) + colb, dst + i * 1024);
        };

        if (t0 < t1) {
            stage_k(t0, 0);

            for (int t = t0; t < t1; t++) {
                int cur = (t - t0) & 1;
                int kv0 = t * 64;
                bool hasnext = (t + 1 < t1);

                // ---- own K(t) landed (issued a full visit ago; cheap wait) ----
                asm volatile("s_waitcnt vmcnt(0)" ::: "memory");
                __builtin_amdgcn_sched_barrier(0);

                // ---- raw barrier: all waves' K(t) landed; all waves done
                //      reading Vt (PV(t-1)) and Kt[cur^1] (QK(t-1)) ----
                __builtin_amdgcn_s_barrier();
                __builtin_amdgcn_sched_barrier(0);

                // ---- issue K(t+1) and V(t) stages (8 DMAs, stay in flight) ----
                if (hasnext) stage_k(t + 1, cur ^ 1);
                stage_v(t);
                __builtin_amdgcn_sched_barrier(0);

                // ---- S^T = K Q^T from LDS (swapped operands) ----
                f32x4 sC[4];
#pragma unroll
                for (int jt = 0; jt < 4; jt++) sC[jt] = (f32x4){0.f, 0.f, 0.f, 0.f};
                const char* kb = (const char*)&Kt[cur][0];
                __builtin_amdgcn_s_setprio(1);
#pragma unroll
                for (int kk = 0; kk < 4; kk++) {
#pragma unroll
                    for (int jt = 0; jt < 4; jt++) {
                        half8 bk = *(const half8*)(kb + (jt * 16 + lr) * 256 +
                                                   ((kk * 64 + lg * 16) ^ ((lr & 7) << 4)));
                        sC[jt] = __builtin_amdgcn_mfma_f32_16x16x32_f16(bk, qa[kk], sC[jt], 0, 0, 0);
                    }
                }
                __builtin_amdgcn_s_setprio(0);

                // ---- lane-local softmax: pv = exp(s*scale - OFF), mask, pack ----
                bool diag = (t == qt);
                unsigned pkr[4][2];
#pragma unroll
                for (int jt = 0; jt < 4; jt++) {
                    float pv[4];
#pragma unroll
                    for (int r = 0; r < 4; r++) {
                        int kv = kv0 + jt * 16 + lg * 4 + r;
                        pv[r] = __expf(sC[jt][r] * scale - OFF);
                        if (diag && (kv > q_abs)) pv[r] = 0.f;
                        lsum += pv[r];
                    }
                    pkr[jt][0] = pkrtz_u32(pv[0], pv[1]);
                    pkr[jt][1] = pkrtz_u32(pv[2], pv[3]);
                }

                // ---- V(t) landed; K(t+1) stays outstanding ----
                if (hasnext) asm volatile("s_waitcnt vmcnt(4)" ::: "memory");
                else         asm volatile("s_waitcnt vmcnt(0)" ::: "memory");
                __builtin_amdgcn_sched_barrier(0);

                // ---- O += P V (P A-fragments in-register; V from LDS) ----
                const char* vb = (const char*)&Vt[0];
                __builtin_amdgcn_s_setprio(1);
#pragma unroll
                for (int kk2 = 0; kk2 < 2; kk2++) {
                    union { unsigned u[4]; half8 h; } pa;
#pragma unroll
                    for (int c = 0; c < 4; c++) {
                        int src = lr + 16 * ((lg & 1) * 2 + (c >> 1));
                        unsigned va = __shfl(pkr[2 * kk2][c & 1], src);
                        unsigned vb2 = __shfl(pkr[2 * kk2 + 1][c & 1], src);
                        pa.u[c] = (lg < 2) ? va : vb2;
                    }
#pragma unroll
                    for (int jo = 0; jo < 8; jo++) {
                        int row = jo * 16 + lr;   // d index
                        half8 bv = *(const half8*)(vb + row * 128 +
                                                   ((kk2 * 64 + lg * 16) ^ ((row & 7) << 4)));
                        oacc[jo] = __builtin_amdgcn_mfma_f32_16x16x32_f16(pa.h, bv, oacc[jo], 0, 0, 0);
                    }
                }
                __builtin_amdgcn_s_setprio(0);
            }
        }

        // ---- lsum: reduce across the 4 lane-groups (kv slices) ----
        lsum += __shfl_xor(lsum, 16);
        lsum += __shfl_xor(lsum, 32);
        if (lane < 16)
            Lab[((size_t)half * NH + h) * L + q0 + lr] = lsum;

        // ---- write unnormalized partial O tile (fp16, owned exclusively) ----
        _Float16* ob = Oab + (size_t)half * L * D;
#pragma unroll
        for (int jo = 0; jo < 8; jo++) {
#pragma unroll
            for (int r = 0; r < 4; r++) {
                int row = q0 + lg * 4 + r;
                int col = h * HD + jo * 16 + lr;
                ob[(size_t)row * D + col] = (_Float16)oacc[jo][r];
            }
        }
    }
}

// ---------------- normalize: aoh = fp16((Oa+Ob) / (La+Lb)) ----------------
__global__ void normalize_o(const _Float16* __restrict__ Oab, const float* __restrict__ Lab,
                            _Float16* __restrict__ out) {
    int i8 = blockIdx.x * blockDim.x + threadIdx.x;   // over L*D/8
    int row = i8 >> 8;                                 // D/8 = 256
    int c8 = (i8 & 255) << 3;
    int h = c8 >> 7;
    half8 a = reinterpret_cast<const half8*>(Oab)[i8];
    half8 b = reinterpret_cast<const half8*>(Oab + (size_t)L * D)[i8];
    float la = Lab[(size_t)h * L + row];
    float lb = Lab[(size_t)(NH + h) * L + row];
    float inv = 1.0f / (la + lb);
    half8 o;
#pragma unroll
    for (int j = 0; j < 8; j++) o[j] = (_Float16)(((float)a[j] + (float)b[j]) * inv);
    reinterpret_cast<half8*>(out)[i8] = o;
}

extern "C" void kernel_launch(void* const* d_in, const int* in_sizes, int n_in,
                              void* d_out, int out_size, void* d_ws, size_t ws_size,
                              hipStream_t stream) {
    const float* x = (const float*)d_in[0];
    const float* wqkv = (const float*)d_in[1];
    const float* wout = (const float*)d_in[2];
    // block_mask (d_in[3]) is tril(ones) == causal; handled analytically.

    _Float16* ws = (_Float16*)d_ws;
    _Float16* xh = ws;                                    // L*D
    _Float16* wqkvh = xh + (size_t)L * D;                 // 3*D*D
    _Float16* wouth = wqkvh + (size_t)3 * D * D;          // D*D
    _Float16* qkh = wouth + (size_t)D * D;                // 2*NH*L*HD
    _Float16* vth = qkh + (size_t)2 * NH * L * HD;        // NH*HD*L
    _Float16* aoh = vth + (size_t)NH * HD * L;            // L*D
    _Float16* Oab = aoh + (size_t)L * D;                  // 2*L*D fp16 partials
    float* Lab = (float*)(Oab + (size_t)2 * L * D);       // 2*NH*L f32
    int* cnt = (int*)(Lab + (size_t)2 * NH * L);          // work-queue counter

    (void)hipMemsetAsync(cnt, 0, 256, stream);

    cvt3_kernel<<<2048, 256, 0, stream>>>(x, wqkv, wout, xh, wqkvh, wouth,
                                          L * D / 4, 3 * D * D / 4, D * D / 4);

    gemm_nt<0><<<dim3(L / 128, 3 * D / 128), 256, 0, stream>>>(
        xh, wqkvh, nullptr, qkh, vth, L, 3 * D, D);

    attn_kernel<<<768, 256, 0, stream>>>(qkh, vth, Oab, Lab, cnt);

    normalize_o<<<L * D / 8 / 256, 256, 0, stream>>>(Oab, Lab, aoh);

    gemm_nt<1><<<dim3(L / 128, D / 128), 256, 0, stream>>>(
        aoh, wouth, (float*)d_out, nullptr, nullptr, L, D, D);
}

// Round 16
// 205.708 us; speedup vs baseline: 2.9989x; 2.9989x over previous
//
#include <hip/hip_runtime.h>

#define L 2048
#define D 2048
#define NH 16
#define HD 128

typedef __attribute__((ext_vector_type(8))) _Float16 half8;
typedef __attribute__((ext_vector_type(4))) float f32x4;

__device__ __forceinline__ void gload_lds16(const void* g, void* l) {
    __builtin_amdgcn_global_load_lds(
        (const __attribute__((address_space(1))) uint32_t*)g,
        (__attribute__((address_space(3))) uint32_t*)l, 16, 0, 0);
}

// pack two f32 -> fp16x2 (RTZ), return as u32
__device__ __forceinline__ unsigned pkrtz_u32(float a, float b) {
    union { __fp16 __attribute__((ext_vector_type(2))) h; unsigned u; } c;
    c.h = __builtin_amdgcn_cvt_pkrtz(a, b);
    return c.u;
}

// ---------------- fused f32 -> fp16 convert of x, W_qkv, W_out ----------------
__global__ void cvt3_kernel(const float* __restrict__ a, const float* __restrict__ b,
                            const float* __restrict__ c, _Float16* __restrict__ oa,
                            _Float16* __restrict__ ob, _Float16* __restrict__ oc,
                            int na, int nb, int nc) {
    int idx = blockIdx.x * blockDim.x + threadIdx.x;
    int stride = gridDim.x * blockDim.x;
    int ntot = na + nb + nc;
    for (int i = idx; i < ntot; i += stride) {
        const float* src; _Float16* dst; int j;
        if (i < na)            { src = a; dst = oa; j = i; }
        else if (i < na + nb)  { src = b; dst = ob; j = i - na; }
        else                   { src = c; dst = oc; j = i - na - nb; }
        float4 v = reinterpret_cast<const float4*>(src)[j];
        union { _Float16 h[4]; uint2 u; } pk;
        pk.h[0] = (_Float16)v.x; pk.h[1] = (_Float16)v.y;
        pk.h[2] = (_Float16)v.z; pk.h[3] = (_Float16)v.w;
        reinterpret_cast<uint2*>(dst)[j] = pk.u;
    }
}

// ---------------- NT GEMM: C[M][N] = A[M][K] * B[N][K]^T ----------------
// r13-exact proven main loop (2-buffer, stage(t+1) -> compute(t) ->
// vmcnt(0)+__syncthreads drain; 73us/706TF). r14's counted-vmcnt pipeline was
// slower (82us); r15's fused norm/rope epilogue spilled to scratch (494us,
// 3GB writes -- 64 sincosf/thread + fat live ranges = rule-#20 spill). Only
// surviving addition: T1 XCD-aware bid swizzle (proved FETCH 102->45MB).
// EPI 0: scatter qkv. q -> qk[0][h][l][d] linear;
//        k -> qk[1][h][l][d^((l&7)<<3)]  (XOR-swizzled for attn K staging);
//        v -> vt[h][d][l^((d&7)<<3)]     (XOR-swizzled for attn V staging).
// EPI 1: write f32 C row-major to Cout
template <int EPI>
__global__ __launch_bounds__(256) void gemm_nt(
    const _Float16* __restrict__ A, const _Float16* __restrict__ B,
    float* __restrict__ Cout, _Float16* __restrict__ qk, _Float16* __restrict__ vt,
    int M, int N, int K)
{
    __shared__ __align__(16) _Float16 Asm[2][128 * 32];   // 2 x 8 KB
    __shared__ __align__(16) _Float16 Bsm[2][128 * 32];   // 2 x 8 KB
    int tid = threadIdx.x;
    int wid = tid >> 6;
    int lane = tid & 63;
    int wr = wid >> 1, wc = wid & 1;

    // T1: XCD-aware block swizzle (nwg divisible by 8 for both launches)
    int nwg = gridDim.x * gridDim.y;
    int bid = blockIdx.y * gridDim.x + blockIdx.x;
    int qch = nwg >> 3;
    int swz = (bid & 7) * qch + (bid >> 3);
    int bx = swz % gridDim.x;
    int by = swz / gridDim.x;
    int m0 = bx * 128;
    int n0 = by * 128;
    int lr = lane & 15;   // row/col within 16
    int lg = lane >> 4;   // group 0..3

    // staging source: thread tid covers tile rows {tid>>2, 64+(tid>>2)}, byte col (tid&3)*16
    const char* Asrc = (const char*)(A + (size_t)(m0 + (tid >> 2)) * K) + (tid & 3) * 16;
    const char* Bsrc = (const char*)(B + (size_t)(n0 + (tid >> 2)) * K) + (tid & 3) * 16;
    size_t rowskip = (size_t)64 * K * 2;   // 64 rows of source, bytes

    auto stage = [&](int k0, int b) {
        const char* as = Asrc + (size_t)k0 * 2;
        const char* bs = Bsrc + (size_t)k0 * 2;
        char* ad = (char*)&Asm[b][0] + wid * 1024;   // + lane*16 by hardware
        char* bd = (char*)&Bsm[b][0] + wid * 1024;
        gload_lds16(as, ad);
        gload_lds16(as + rowskip, ad + 4096);
        gload_lds16(bs, bd);
        gload_lds16(bs + rowskip, bd + 4096);
    };

    f32x4 acc[4][4];
#pragma unroll
    for (int i = 0; i < 4; i++)
#pragma unroll
        for (int j = 0; j < 4; j++)
            acc[i][j] = (f32x4){0.f, 0.f, 0.f, 0.f};

    int NT = K / 32;
    stage(0, 0);
    asm volatile("s_waitcnt vmcnt(0)" ::: "memory");
    __syncthreads();

    for (int t = 0; t < NT; t++) {
        int cur = t & 1;
        if (t + 1 < NT) stage((t + 1) * 32, cur ^ 1);

        const char* ab = (const char*)&Asm[cur][0] + (wr * 64 + lr) * 64 + lg * 16;
        const char* bb = (const char*)&Bsm[cur][0] + (wc * 64 + lr) * 64 + lg * 16;
        half8 a[4], b[4];
#pragma unroll
        for (int i = 0; i < 4; i++) a[i] = *(const half8*)(ab + i * 1024);
#pragma unroll
        for (int j = 0; j < 4; j++) b[j] = *(const half8*)(bb + j * 1024);
#pragma unroll
        for (int i = 0; i < 4; i++)
#pragma unroll
            for (int j = 0; j < 4; j++)
                acc[i][j] = __builtin_amdgcn_mfma_f32_16x16x32_f16(a[i], b[j], acc[i][j], 0, 0, 0);

        asm volatile("s_waitcnt vmcnt(0)" ::: "memory");
        __syncthreads();
    }

#pragma unroll
    for (int i = 0; i < 4; i++) {
#pragma unroll
        for (int j = 0; j < 4; j++) {
#pragma unroll
            for (int r = 0; r < 4; r++) {
                int row = m0 + wr * 64 + i * 16 + lg * 4 + r;  // C layout: row=(lane>>4)*4+reg
                int col = n0 + wc * 64 + j * 16 + lr;          //           col=lane&15
                float v = acc[i][j][r];
                if (EPI == 0) {
                    int t = col >> 11;
                    int w2 = col & 2047;
                    int h = w2 >> 7, d = w2 & 127;
                    if (t == 0) {
                        qk[(((size_t)h) * L + row) * HD + d] = (_Float16)v;
                    } else if (t == 1) {
                        int dsw = d ^ ((row & 7) << 3);   // pre-swizzle for attn K staging
                        qk[(((size_t)NH + h) * L + row) * HD + dsw] = (_Float16)v;
                    } else {
                        int lsw = row ^ ((d & 7) << 3);   // pre-swizzle for attn V staging
                        vt[((size_t)h * HD + d) * L + lsw] = (_Float16)v;
                    }
                } else {
                    Cout[(size_t)row * N + col] = v;
                }
            }
        }
    }
}

// ---------------- fused RMSNorm + RoPE on q and k planes (in place) ----------------
// k plane is stored element-swizzled (d' = d ^ ((l&7)<<3)); RMS sum is
// permutation-invariant and RoPE pairs stay adjacent, so only the pair
// index used for the frequency changes: i = lane ^ ((l&7)<<2).
__global__ void norm_rope(_Float16* __restrict__ qk) {
    int wid = threadIdx.x >> 6, lane = threadIdx.x & 63;
    int row = blockIdx.x * 4 + wid;      // 0 .. 2*NH*L-1
    int l = row & (L - 1);
    int th = row >> 11;                  // t*NH + h, 0..31
    _Float16* p = qk + ((size_t)th * L + l) * HD + lane * 2;
    float x0 = (float)p[0];
    float x1 = (float)p[1];
    float ss = x0 * x0 + x1 * x1;
#pragma unroll
    for (int off = 1; off < 64; off <<= 1) ss += __shfl_xor(ss, off);
    float r = rsqrtf(ss * (1.0f / 128.0f) + 1e-5f);
    float n0 = x0 * r, n1 = x1 * r;
    int i = (th >= NH) ? (lane ^ ((l & 7) << 2)) : lane;   // swizzle-aware pair index
    float freq = expf(-(float)(2 * i) * (1.0f / 128.0f) * logf(100000.0f));
    float ang = (float)l * freq;
    float s, c;
    sincosf(ang, &s, &c);
    p[0] = (_Float16)(n1 * c - n0 * s);
    p[1] = (_Float16)(n1 * s + n0 * c);
}

// ---------------- causal flash attention, v11: V via LDS ----------------
// (unchanged from r13 -- K+V staged in LDS, swapped QK^T, in-register P,
// counted vmcnt + raw barrier, dynamic work queue, half partials)
__global__ __launch_bounds__(256, 3) void attn_kernel(
    const _Float16* __restrict__ qk, const _Float16* __restrict__ vt,
    _Float16* __restrict__ Oab, float* __restrict__ Lab, int* __restrict__ cnt)
{
    __shared__ __align__(16) _Float16 Kt[2][64 * HD];     // 2 x 16 KB
    __shared__ __align__(16) _Float16 Vt[64 * HD];        // 16 KB, single-buffered
    __shared__ int sh_i;
    int wid = threadIdx.x >> 6, lane = threadIdx.x & 63;
    int lr = lane & 15, lg = lane >> 4;

    const float scale = 0.08838834764831845f;  // 1/sqrt(128)
    const float OFF = 4.0f;                    // static exp offset (absolute)

    for (;;) {
        __syncthreads();   // full drain between items (protects sh_i + Kt/Vt reuse)
        if (threadIdx.x == 0) sh_i = atomicAdd(cnt, 1);
        __syncthreads();
        int item = sh_i;
        if (item >= 1024) return;

        // decode big-first: qt descending; 32 items (16h x 2half) per qt
        int qt = 31 - (item >> 5);
        int h = (item >> 1) & 15;
        int half = item & 1;
        int n = qt + 1;
        int mid = (n + 1) >> 1;
        int t0 = half ? mid : 0;
        int t1 = half ? n : mid;
        int q0 = qt * 64 + wid * 16;
        int q_abs = q0 + lr;               // this lane's q-row (swapped layout)

        const _Float16* qn = qk + (size_t)h * L * HD;              // q plane
        const _Float16* kn = qk + ((size_t)(NH + h) * L) * HD;     // k plane (swizzled)
        const _Float16* vp = vt + (size_t)h * HD * L;              // v^T plane (swizzled)

        half8 qa[4];
#pragma unroll
        for (int kk = 0; kk < 4; kk++)
            qa[kk] = *reinterpret_cast<const half8*>(qn + (size_t)(q0 + lr) * HD + kk * 32 + lg * 8);

        f32x4 oacc[8];
#pragma unroll
        for (int jo = 0; jo < 8; jo++) oacc[jo] = (f32x4){0.f, 0.f, 0.f, 0.f};
        float lsum = 0.f;                  // per-lane scalar (q-row lr, this lane's kv slice)

        // per-wave QUARTER K stage: wave w copies kv rows 16w..16w+15 (4 KB, 4 DMAs)
        auto stage_k = [&](int t, int b) {
            const char* src = (const char*)(kn + (size_t)t * 64 * HD) + wid * 4096 + lane * 16;
            char* dst = (char*)&Kt[b][0] + wid * 4096;
#pragma unroll
            for (int i = 0; i < 4; i++)
                gload_lds16(src + i * 1024, dst + i * 1024);
        };
        // per-wave QUARTER V stage: tile [128 d][64 kv], 128B per d-row.
        auto stage_v = [&](int t) {
            const char* vpb = (const char*)vp + (size_t)t * 128;   // kv0*2 bytes
            char* dst = (char*)&Vt[0] + wid * 4096;
            int dbase = wid * 32 + (lane >> 3);
            int colb = (lane & 7) * 16;
#pragma unroll
            for (int i = 0; i < 4; i++)
                gload_lds16(vpb + (size_t)(dbase + i * 8) * (L * 2) + colb, dst + i * 1024);
        };

        if (t0 < t1) {
            stage_k(t0, 0);

            for (int t = t0; t < t1; t++) {
                int cur = (t - t0) & 1;
                int kv0 = t * 64;
                bool hasnext = (t + 1 < t1);

                // ---- own K(t) landed (issued a full visit ago; cheap wait) ----
                asm volatile("s_waitcnt vmcnt(0)" ::: "memory");
                __builtin_amdgcn_sched_barrier(0);

                // ---- raw barrier: all waves' K(t) landed; all waves done
                //      reading Vt (PV(t-1)) and Kt[cur^1] (QK(t-1)) ----
                __builtin_amdgcn_s_barrier();
                __builtin_amdgcn_sched_barrier(0);

                // ---- issue K(t+1) and V(t) stages (8 DMAs, stay in flight) ----
                if (hasnext) stage_k(t + 1, cur ^ 1);
                stage_v(t);
                __builtin_amdgcn_sched_barrier(0);

                // ---- S^T = K Q^T from LDS (swapped operands) ----
                f32x4 sC[4];
#pragma unroll
                for (int jt = 0; jt < 4; jt++) sC[jt] = (f32x4){0.f, 0.f, 0.f, 0.f};
                const char* kb = (const char*)&Kt[cur][0];
                __builtin_amdgcn_s_setprio(1);
#pragma unroll
                for (int kk = 0; kk < 4; kk++) {
#pragma unroll
                    for (int jt = 0; jt < 4; jt++) {
                        half8 bk = *(const half8*)(kb + (jt * 16 + lr) * 256 +
                                                   ((kk * 64 + lg * 16) ^ ((lr & 7) << 4)));
                        sC[jt] = __builtin_amdgcn_mfma_f32_16x16x32_f16(bk, qa[kk], sC[jt], 0, 0, 0);
                    }
                }
                __builtin_amdgcn_s_setprio(0);

                // ---- lane-local softmax: pv = exp(s*scale - OFF), mask, pack ----
                bool diag = (t == qt);
                unsigned pkr[4][2];
#pragma unroll
                for (int jt = 0; jt < 4; jt++) {
                    float pv[4];
#pragma unroll
                    for (int r = 0; r < 4; r++) {
                        int kv = kv0 + jt * 16 + lg * 4 + r;
                        pv[r] = __expf(sC[jt][r] * scale - OFF);
                        if (diag && (kv > q_abs)) pv[r] = 0.f;
                        lsum += pv[r];
                    }
                    pkr[jt][0] = pkrtz_u32(pv[0], pv[1]);
                    pkr[jt][1] = pkrtz_u32(pv[2], pv[3]);
                }

                // ---- V(t) landed; K(t+1) stays outstanding ----
                if (hasnext) asm volatile("s_waitcnt vmcnt(4)" ::: "memory");
                else         asm volatile("s_waitcnt vmcnt(0)" ::: "memory");
                __builtin_amdgcn_sched_barrier(0);

                // ---- O += P V (P A-fragments in-register; V from LDS) ----
                const char* vb = (const char*)&Vt[0];
                __builtin_amdgcn_s_setprio(1);
#pragma unroll
                for (int kk2 = 0; kk2 < 2; kk2++) {
                    union { unsigned u[4]; half8 h; } pa;
#pragma unroll
                    for (int c = 0; c < 4; c++) {
                        int src = lr + 16 * ((lg & 1) * 2 + (c >> 1));
                        unsigned va = __shfl(pkr[2 * kk2][c & 1], src);
                        unsigned vb2 = __shfl(pkr[2 * kk2 + 1][c & 1], src);
                        pa.u[c] = (lg < 2) ? va : vb2;
                    }
#pragma unroll
                    for (int jo = 0; jo < 8; jo++) {
                        int row = jo * 16 + lr;   // d index
                        half8 bv = *(const half8*)(vb + row * 128 +
                                                   ((kk2 * 64 + lg * 16) ^ ((row & 7) << 4)));
                        oacc[jo] = __builtin_amdgcn_mfma_f32_16x16x32_f16(pa.h, bv, oacc[jo], 0, 0, 0);
                    }
                }
                __builtin_amdgcn_s_setprio(0);
            }
        }

        // ---- lsum: reduce across the 4 lane-groups (kv slices) ----
        lsum += __shfl_xor(lsum, 16);
        lsum += __shfl_xor(lsum, 32);
        if (lane < 16)
            Lab[((size_t)half * NH + h) * L + q0 + lr] = lsum;

        // ---- write unnormalized partial O tile (fp16, owned exclusively) ----
        _Float16* ob = Oab + (size_t)half * L * D;
#pragma unroll
        for (int jo = 0; jo < 8; jo++) {
#pragma unroll
            for (int r = 0; r < 4; r++) {
                int row = q0 + lg * 4 + r;
                int col = h * HD + jo * 16 + lr;
                ob[(size_t)row * D + col] = (_Float16)oacc[jo][r];
            }
        }
    }
}

// ---------------- normalize: aoh = fp16((Oa+Ob) / (La+Lb)) ----------------
__global__ void normalize_o(const _Float16* __restrict__ Oab, const float* __restrict__ Lab,
                            _Float16* __restrict__ out) {
    int i8 = blockIdx.x * blockDim.x + threadIdx.x;   // over L*D/8
    int row = i8 >> 8;                                 // D/8 = 256
    int c8 = (i8 & 255) << 3;
    int h = c8 >> 7;
    half8 a = reinterpret_cast<const half8*>(Oab)[i8];
    half8 b = reinterpret_cast<const half8*>(Oab + (size_t)L * D)[i8];
    float la = Lab[(size_t)h * L + row];
    float lb = Lab[(size_t)(NH + h) * L + row];
    float inv = 1.0f / (la + lb);
    half8 o;
#pragma unroll
    for (int j = 0; j < 8; j++) o[j] = (_Float16)(((float)a[j] + (float)b[j]) * inv);
    reinterpret_cast<half8*>(out)[i8] = o;
}

extern "C" void kernel_launch(void* const* d_in, const int* in_sizes, int n_in,
                              void* d_out, int out_size, void* d_ws, size_t ws_size,
                              hipStream_t stream) {
    const float* x = (const float*)d_in[0];
    const float* wqkv = (const float*)d_in[1];
    const float* wout = (const float*)d_in[2];
    // block_mask (d_in[3]) is tril(ones) == causal; handled analytically.

    _Float16* ws = (_Float16*)d_ws;
    _Float16* xh = ws;                                    // L*D
    _Float16* wqkvh = xh + (size_t)L * D;                 // 3*D*D
    _Float16* wouth = wqkvh + (size_t)3 * D * D;          // D*D
    _Float16* qkh = wouth + (size_t)D * D;                // 2*NH*L*HD
    _Float16* vth = qkh + (size_t)2 * NH * L * HD;        // NH*HD*L
    _Float16* aoh = vth + (size_t)NH * HD * L;            // L*D
    _Float16* Oab = aoh + (size_t)L * D;                  // 2*L*D fp16 partials
    float* Lab = (float*)(Oab + (size_t)2 * L * D);       // 2*NH*L f32
    int* cnt = (int*)(Lab + (size_t)2 * NH * L);          // work-queue counter

    (void)hipMemsetAsync(cnt, 0, 256, stream);

    cvt3_kernel<<<2048, 256, 0, stream>>>(x, wqkv, wout, xh, wqkvh, wouth,
                                          L * D / 4, 3 * D * D / 4, D * D / 4);

    gemm_nt<0><<<dim3(L / 128, 3 * D / 128), 256, 0, stream>>>(
        xh, wqkvh, nullptr, qkh, vth, L, 3 * D, D);

    norm_rope<<<2 * NH * L / 4, 256, 0, stream>>>(qkh);

    attn_kernel<<<768, 256, 0, stream>>>(qkh, vth, Oab, Lab, cnt);

    normalize_o<<<L * D / 8 / 256, 256, 0, stream>>>(Oab, Lab, aoh);

    gemm_nt<1><<<dim3(L / 128, D / 128), 256, 0, stream>>>(
        aoh, wouth, (float*)d_out, nullptr, nullptr, L, D, D);
}

// Round 17
// 193.836 us; speedup vs baseline: 3.1826x; 1.0612x over previous
//
#include <hip/hip_runtime.h>

#define L 2048
#define D 2048
#define NH 16
#define HD 128

typedef __attribute__((ext_vector_type(8))) _Float16 half8;
typedef __attribute__((ext_vector_type(4))) float f32x4;

__device__ __forceinline__ void gload_lds16(const void* g, void* l) {
    __builtin_amdgcn_global_load_lds(
        (const __attribute__((address_space(1))) uint32_t*)g,
        (__attribute__((address_space(3))) uint32_t*)l, 16, 0, 0);
}

// pack two f32 -> fp16x2 (RTZ), return as u32
__device__ __forceinline__ unsigned pkrtz_u32(float a, float b) {
    union { __fp16 __attribute__((ext_vector_type(2))) h; unsigned u; } c;
    c.h = __builtin_amdgcn_cvt_pkrtz(a, b);
    return c.u;
}

// ---------------- fused f32 -> fp16 convert of x, W_qkv, W_out ----------------
__global__ void cvt3_kernel(const float* __restrict__ a, const float* __restrict__ b,
                            const float* __restrict__ c, _Float16* __restrict__ oa,
                            _Float16* __restrict__ ob, _Float16* __restrict__ oc,
                            int na, int nb, int nc) {
    int idx = blockIdx.x * blockDim.x + threadIdx.x;
    int stride = gridDim.x * blockDim.x;
    int ntot = na + nb + nc;
    for (int i = idx; i < ntot; i += stride) {
        const float* src; _Float16* dst; int j;
        if (i < na)            { src = a; dst = oa; j = i; }
        else if (i < na + nb)  { src = b; dst = ob; j = i - na; }
        else                   { src = c; dst = oc; j = i - na - nb; }
        float4 v = reinterpret_cast<const float4*>(src)[j];
        union { _Float16 h[4]; uint2 u; } pk;
        pk.h[0] = (_Float16)v.x; pk.h[1] = (_Float16)v.y;
        pk.h[2] = (_Float16)v.z; pk.h[3] = (_Float16)v.w;
        reinterpret_cast<uint2*>(dst)[j] = pk.u;
    }
}

// ---------------- NT GEMM (QKV): C[M][N] = A[M][K] * B[N][K]^T ----------------
// r13-exact proven structure (73us/706TF): 2-buffer, stage(t+1) -> compute(t)
// -> vmcnt(0)+__syncthreads drain. T1 XCD swizzle REMOVED: r13 (no T1) = 73us
// vs r16 (T1) = 80us -- FETCH halved but time rose; HBM was never the limiter.
// 128x128 block tile, 4 waves 2x2, 4x4 16x16x32 fragments per wave, BK=32.
// Epilogue scatters qkv: q -> qk[0][h][l][d] linear;
//   k -> qk[1][h][l][d^((l&7)<<3)]  (XOR-swizzled for attn K staging);
//   v -> vt[h][d][l^((d&7)<<3)]     (XOR-swizzled for attn V staging).
__global__ __launch_bounds__(256) void gemm_nt(
    const _Float16* __restrict__ A, const _Float16* __restrict__ B,
    _Float16* __restrict__ qk, _Float16* __restrict__ vt,
    int M, int N, int K)
{
    __shared__ __align__(16) _Float16 Asm[2][128 * 32];   // 2 x 8 KB
    __shared__ __align__(16) _Float16 Bsm[2][128 * 32];   // 2 x 8 KB
    int tid = threadIdx.x;
    int wid = tid >> 6;
    int lane = tid & 63;
    int wr = wid >> 1, wc = wid & 1;
    int m0 = blockIdx.x * 128;
    int n0 = blockIdx.y * 128;
    int lr = lane & 15;   // row/col within 16
    int lg = lane >> 4;   // group 0..3

    // staging source: thread tid covers tile rows {tid>>2, 64+(tid>>2)}, byte col (tid&3)*16
    const char* Asrc = (const char*)(A + (size_t)(m0 + (tid >> 2)) * K) + (tid & 3) * 16;
    const char* Bsrc = (const char*)(B + (size_t)(n0 + (tid >> 2)) * K) + (tid & 3) * 16;
    size_t rowskip = (size_t)64 * K * 2;   // 64 rows of source, bytes

    auto stage = [&](int k0, int b) {
        const char* as = Asrc + (size_t)k0 * 2;
        const char* bs = Bsrc + (size_t)k0 * 2;
        char* ad = (char*)&Asm[b][0] + wid * 1024;   // + lane*16 by hardware
        char* bd = (char*)&Bsm[b][0] + wid * 1024;
        gload_lds16(as, ad);
        gload_lds16(as + rowskip, ad + 4096);
        gload_lds16(bs, bd);
        gload_lds16(bs + rowskip, bd + 4096);
    };

    f32x4 acc[4][4];
#pragma unroll
    for (int i = 0; i < 4; i++)
#pragma unroll
        for (int j = 0; j < 4; j++)
            acc[i][j] = (f32x4){0.f, 0.f, 0.f, 0.f};

    int NT = K / 32;
    stage(0, 0);
    asm volatile("s_waitcnt vmcnt(0)" ::: "memory");
    __syncthreads();

    for (int t = 0; t < NT; t++) {
        int cur = t & 1;
        if (t + 1 < NT) stage((t + 1) * 32, cur ^ 1);

        const char* ab = (const char*)&Asm[cur][0] + (wr * 64 + lr) * 64 + lg * 16;
        const char* bb = (const char*)&Bsm[cur][0] + (wc * 64 + lr) * 64 + lg * 16;
        half8 a[4], b[4];
#pragma unroll
        for (int i = 0; i < 4; i++) a[i] = *(const half8*)(ab + i * 1024);
#pragma unroll
        for (int j = 0; j < 4; j++) b[j] = *(const half8*)(bb + j * 1024);
#pragma unroll
        for (int i = 0; i < 4; i++)
#pragma unroll
            for (int j = 0; j < 4; j++)
                acc[i][j] = __builtin_amdgcn_mfma_f32_16x16x32_f16(a[i], b[j], acc[i][j], 0, 0, 0);

        asm volatile("s_waitcnt vmcnt(0)" ::: "memory");
        __syncthreads();
    }

#pragma unroll
    for (int i = 0; i < 4; i++) {
#pragma unroll
        for (int j = 0; j < 4; j++) {
#pragma unroll
            for (int r = 0; r < 4; r++) {
                int row = m0 + wr * 64 + i * 16 + lg * 4 + r;  // C layout: row=(lane>>4)*4+reg
                int col = n0 + wc * 64 + j * 16 + lr;          //           col=lane&15
                float v = acc[i][j][r];
                int t = col >> 11;
                int w2 = col & 2047;
                int h = w2 >> 7, d = w2 & 127;
                if (t == 0) {
                    qk[(((size_t)h) * L + row) * HD + d] = (_Float16)v;
                } else if (t == 1) {
                    int dsw = d ^ ((row & 7) << 3);   // pre-swizzle for attn K staging
                    qk[(((size_t)NH + h) * L + row) * HD + dsw] = (_Float16)v;
                } else {
                    int lsw = row ^ ((d & 7) << 3);   // pre-swizzle for attn V staging
                    vt[((size_t)h * HD + d) * L + lsw] = (_Float16)v;
                }
            }
        }
    }
}

// ---------------- output-projection GEMM: Cout[M][N] = A[M][K] * B[N][K]^T ----------------
// 64x128 block tile -> grid (M/64, N/128) = 512 blocks = 2 blocks/CU (the old
// 128x128 gave 256 blocks = 1/CU: the per-iter drain stall was fully naked).
// Same proven 2-buffer drain structure. 4 waves each own 64x32 (acc[4][2]);
// stage = 3 DMAs/thread (A 1, B 2); LDS 24 KB.
__global__ __launch_bounds__(256) void gemm_out(
    const _Float16* __restrict__ A, const _Float16* __restrict__ B,
    float* __restrict__ Cout, int M, int N, int K)
{
    __shared__ __align__(16) _Float16 Asm[2][64 * 32];    // 2 x 4 KB
    __shared__ __align__(16) _Float16 Bsm[2][128 * 32];   // 2 x 8 KB
    int tid = threadIdx.x;
    int wid = tid >> 6;
    int lane = tid & 63;
    int m0 = blockIdx.x * 64;
    int n0 = blockIdx.y * 128;
    int lr = lane & 15;
    int lg = lane >> 4;

    const char* Asrc = (const char*)(A + (size_t)(m0 + (tid >> 2)) * K) + (tid & 3) * 16;
    const char* Bsrc = (const char*)(B + (size_t)(n0 + (tid >> 2)) * K) + (tid & 3) * 16;
    size_t rowskip = (size_t)64 * K * 2;

    auto stage = [&](int k0, int b) {
        const char* as = Asrc + (size_t)k0 * 2;
        const char* bs = Bsrc + (size_t)k0 * 2;
        char* ad = (char*)&Asm[b][0] + wid * 1024;   // + lane*16 by hardware
        char* bd = (char*)&Bsm[b][0] + wid * 1024;
        gload_lds16(as, ad);                 // A rows 0..63: LDS byte tid*16
        gload_lds16(bs, bd);                 // B rows 0..63
        gload_lds16(bs + rowskip, bd + 4096); // B rows 64..127
    };

    f32x4 acc[4][2];
#pragma unroll
    for (int i = 0; i < 4; i++)
#pragma unroll
        for (int j = 0; j < 2; j++)
            acc[i][j] = (f32x4){0.f, 0.f, 0.f, 0.f};

    int NT = K / 32;
    stage(0, 0);
    asm volatile("s_waitcnt vmcnt(0)" ::: "memory");
    __syncthreads();

    for (int t = 0; t < NT; t++) {
        int cur = t & 1;
        if (t + 1 < NT) stage((t + 1) * 32, cur ^ 1);

        const char* ab = (const char*)&Asm[cur][0] + lr * 64 + lg * 16;
        const char* bb = (const char*)&Bsm[cur][0] + (wid * 32 + lr) * 64 + lg * 16;
        half8 a[4], b[2];
#pragma unroll
        for (int i = 0; i < 4; i++) a[i] = *(const half8*)(ab + i * 1024);
#pragma unroll
        for (int j = 0; j < 2; j++) b[j] = *(const half8*)(bb + j * 1024);
#pragma unroll
        for (int i = 0; i < 4; i++)
#pragma unroll
            for (int j = 0; j < 2; j++)
                acc[i][j] = __builtin_amdgcn_mfma_f32_16x16x32_f16(a[i], b[j], acc[i][j], 0, 0, 0);

        asm volatile("s_waitcnt vmcnt(0)" ::: "memory");
        __syncthreads();
    }

#pragma unroll
    for (int i = 0; i < 4; i++) {
#pragma unroll
        for (int j = 0; j < 2; j++) {
#pragma unroll
            for (int r = 0; r < 4; r++) {
                int row = m0 + i * 16 + lg * 4 + r;
                int col = n0 + wid * 32 + j * 16 + lr;
                Cout[(size_t)row * N + col] = acc[i][j][r];
            }
        }
    }
}

// ---------------- fused RMSNorm + RoPE on q and k planes (in place) ----------------
__global__ void norm_rope(_Float16* __restrict__ qk) {
    int wid = threadIdx.x >> 6, lane = threadIdx.x & 63;
    int row = blockIdx.x * 4 + wid;      // 0 .. 2*NH*L-1
    int l = row & (L - 1);
    int th = row >> 11;                  // t*NH + h, 0..31
    _Float16* p = qk + ((size_t)th * L + l) * HD + lane * 2;
    float x0 = (float)p[0];
    float x1 = (float)p[1];
    float ss = x0 * x0 + x1 * x1;
#pragma unroll
    for (int off = 1; off < 64; off <<= 1) ss += __shfl_xor(ss, off);
    float r = rsqrtf(ss * (1.0f / 128.0f) + 1e-5f);
    float n0 = x0 * r, n1 = x1 * r;
    int i = (th >= NH) ? (lane ^ ((l & 7) << 2)) : lane;   // swizzle-aware pair index
    float freq = expf(-(float)(2 * i) * (1.0f / 128.0f) * logf(100000.0f));
    float ang = (float)l * freq;
    float s, c;
    sincosf(ang, &s, &c);
    p[0] = (_Float16)(n1 * c - n0 * s);
    p[1] = (_Float16)(n1 * s + n0 * c);
}

// ---------------- causal flash attention, v11: V via LDS ----------------
// (unchanged from r13 -- K+V staged in LDS, swapped QK^T, in-register P,
// counted vmcnt + raw barrier, dynamic work queue, half partials)
__global__ __launch_bounds__(256, 3) void attn_kernel(
    const _Float16* __restrict__ qk, const _Float16* __restrict__ vt,
    _Float16* __restrict__ Oab, float* __restrict__ Lab, int* __restrict__ cnt)
{
    __shared__ __align__(16) _Float16 Kt[2][64 * HD];     // 2 x 16 KB
    __shared__ __align__(16) _Float16 Vt[64 * HD];        // 16 KB, single-buffered
    __shared__ int sh_i;
    int wid = threadIdx.x >> 6, lane = threadIdx.x & 63;
    int lr = lane & 15, lg = lane >> 4;

    const float scale = 0.08838834764831845f;  // 1/sqrt(128)
    const float OFF = 4.0f;                    // static exp offset (absolute)

    for (;;) {
        __syncthreads();   // full drain between items (protects sh_i + Kt/Vt reuse)
        if (threadIdx.x == 0) sh_i = atomicAdd(cnt, 1);
        __syncthreads();
        int item = sh_i;
        if (item >= 1024) return;

        // decode big-first: qt descending; 32 items (16h x 2half) per qt
        int qt = 31 - (item >> 5);
        int h = (item >> 1) & 15;
        int half = item & 1;
        int n = qt + 1;
        int mid = (n + 1) >> 1;
        int t0 = half ? mid : 0;
        int t1 = half ? n : mid;
        int q0 = qt * 64 + wid * 16;
        int q_abs = q0 + lr;               // this lane's q-row (swapped layout)

        const _Float16* qn = qk + (size_t)h * L * HD;              // q plane
        const _Float16* kn = qk + ((size_t)(NH + h) * L) * HD;     // k plane (swizzled)
        const _Float16* vp = vt + (size_t)h * HD * L;              // v^T plane (swizzled)

        half8 qa[4];
#pragma unroll
        for (int kk = 0; kk < 4; kk++)
            qa[kk] = *reinterpret_cast<const half8*>(qn + (size_t)(q0 + lr) * HD + kk * 32 + lg * 8);

        f32x4 oacc[8];
#pragma unroll
        for (int jo = 0; jo < 8; jo++) oacc[jo] = (f32x4){0.f, 0.f, 0.f, 0.f};
        float lsum = 0.f;                  // per-lane scalar (q-row lr, this lane's kv slice)

        // per-wave QUARTER K stage: wave w copies kv rows 16w..16w+15 (4 KB, 4 DMAs)
        auto stage_k = [&](int t, int b) {
            const char* src = (const char*)(kn + (size_t)t * 64 * HD) + wid * 4096 + lane * 16;
            char* dst = (char*)&Kt[b][0] + wid * 4096;
#pragma unroll
            for (int i = 0; i < 4; i++)
                gload_lds16(src + i * 1024, dst + i * 1024);
        };
        // per-wave QUARTER V stage: tile [128 d][64 kv], 128B per d-row.
        auto stage_v = [&](int t) {
            const char* vpb = (const char*)vp + (size_t)t * 128;   // kv0*2 bytes
            char* dst = (char*)&Vt[0] + wid * 4096;
            int dbase = wid * 32 + (lane >> 3);
            int colb = (lane & 7) * 16;
#pragma unroll
            for (int i = 0; i < 4; i++)
                gload_lds16(vpb + (size_t)(dbase + i * 8) * (L * 2) + colb, dst + i * 1024);
        };

        if (t0 < t1) {
            stage_k(t0, 0);

            for (int t = t0; t < t1; t++) {
                int cur = (t - t0) & 1;
                int kv0 = t * 64;
                bool hasnext = (t + 1 < t1);

                // ---- own K(t) landed (issued a full visit ago; cheap wait) ----
                asm volatile("s_waitcnt vmcnt(0)" ::: "memory");
                __builtin_amdgcn_sched_barrier(0);

                // ---- raw barrier: all waves' K(t) landed; all waves done
                //      reading Vt (PV(t-1)) and Kt[cur^1] (QK(t-1)) ----
                __builtin_amdgcn_s_barrier();
                __builtin_amdgcn_sched_barrier(0);

                // ---- issue K(t+1) and V(t) stages (8 DMAs, stay in flight) ----
                if (hasnext) stage_k(t + 1, cur ^ 1);
                stage_v(t);
                __builtin_amdgcn_sched_barrier(0);

                // ---- S^T = K Q^T from LDS (swapped operands) ----
                f32x4 sC[4];
#pragma unroll
                for (int jt = 0; jt < 4; jt++) sC[jt] = (f32x4){0.f, 0.f, 0.f, 0.f};
                const char* kb = (const char*)&Kt[cur][0];
                __builtin_amdgcn_s_setprio(1);
#pragma unroll
                for (int kk = 0; kk < 4; kk++) {
#pragma unroll
                    for (int jt = 0; jt < 4; jt++) {
                        half8 bk = *(const half8*)(kb + (jt * 16 + lr) * 256 +
                                                   ((kk * 64 + lg * 16) ^ ((lr & 7) << 4)));
                        sC[jt] = __builtin_amdgcn_mfma_f32_16x16x32_f16(bk, qa[kk], sC[jt], 0, 0, 0);
                    }
                }
                __builtin_amdgcn_s_setprio(0);

                // ---- lane-local softmax: pv = exp(s*scale - OFF), mask, pack ----
                bool diag = (t == qt);
                unsigned pkr[4][2];
#pragma unroll
                for (int jt = 0; jt < 4; jt++) {
                    float pv[4];
#pragma unroll
                    for (int r = 0; r < 4; r++) {
                        int kv = kv0 + jt * 16 + lg * 4 + r;
                        pv[r] = __expf(sC[jt][r] * scale - OFF);
                        if (diag && (kv > q_abs)) pv[r] = 0.f;
                        lsum += pv[r];
                    }
                    pkr[jt][0] = pkrtz_u32(pv[0], pv[1]);
                    pkr[jt][1] = pkrtz_u32(pv[2], pv[3]);
                }

                // ---- V(t) landed; K(t+1) stays outstanding ----
                if (hasnext) asm volatile("s_waitcnt vmcnt(4)" ::: "memory");
                else         asm volatile("s_waitcnt vmcnt(0)" ::: "memory");
                __builtin_amdgcn_sched_barrier(0);

                // ---- O += P V (P A-fragments in-register; V from LDS) ----
                const char* vb = (const char*)&Vt[0];
                __builtin_amdgcn_s_setprio(1);
#pragma unroll
                for (int kk2 = 0; kk2 < 2; kk2++) {
                    union { unsigned u[4]; half8 h; } pa;
#pragma unroll
                    for (int c = 0; c < 4; c++) {
                        int src = lr + 16 * ((lg & 1) * 2 + (c >> 1));
                        unsigned va = __shfl(pkr[2 * kk2][c & 1], src);
                        unsigned vb2 = __shfl(pkr[2 * kk2 + 1][c & 1], src);
                        pa.u[c] = (lg < 2) ? va : vb2;
                    }
#pragma unroll
                    for (int jo = 0; jo < 8; jo++) {
                        int row = jo * 16 + lr;   // d index
                        half8 bv = *(const half8*)(vb + row * 128 +
                                                   ((kk2 * 64 + lg * 16) ^ ((row & 7) << 4)));
                        oacc[jo] = __builtin_amdgcn_mfma_f32_16x16x32_f16(pa.h, bv, oacc[jo], 0, 0, 0);
                    }
                }
                __builtin_amdgcn_s_setprio(0);
            }
        }

        // ---- lsum: reduce across the 4 lane-groups (kv slices) ----
        lsum += __shfl_xor(lsum, 16);
        lsum += __shfl_xor(lsum, 32);
        if (lane < 16)
            Lab[((size_t)half * NH + h) * L + q0 + lr] = lsum;

        // ---- write unnormalized partial O tile (fp16, owned exclusively) ----
        _Float16* ob = Oab + (size_t)half * L * D;
#pragma unroll
        for (int jo = 0; jo < 8; jo++) {
#pragma unroll
            for (int r = 0; r < 4; r++) {
                int row = q0 + lg * 4 + r;
                int col = h * HD + jo * 16 + lr;
                ob[(size_t)row * D + col] = (_Float16)oacc[jo][r];
            }
        }
    }
}

// ---------------- normalize: aoh = fp16((Oa+Ob) / (La+Lb)) ----------------
__global__ void normalize_o(const _Float16* __restrict__ Oab, const float* __restrict__ Lab,
                            _Float16* __restrict__ out) {
    int i8 = blockIdx.x * blockDim.x + threadIdx.x;   // over L*D/8
    int row = i8 >> 8;                                 // D/8 = 256
    int c8 = (i8 & 255) << 3;
    int h = c8 >> 7;
    half8 a = reinterpret_cast<const half8*>(Oab)[i8];
    half8 b = reinterpret_cast<const half8*>(Oab + (size_t)L * D)[i8];
    float la = Lab[(size_t)h * L + row];
    float lb = Lab[(size_t)(NH + h) * L + row];
    float inv = 1.0f / (la + lb);
    half8 o;
#pragma unroll
    for (int j = 0; j < 8; j++) o[j] = (_Float16)(((float)a[j] + (float)b[j]) * inv);
    reinterpret_cast<half8*>(out)[i8] = o;
}

extern "C" void kernel_launch(void* const* d_in, const int* in_sizes, int n_in,
                              void* d_out, int out_size, void* d_ws, size_t ws_size,
                              hipStream_t stream) {
    const float* x = (const float*)d_in[0];
    const float* wqkv = (const float*)d_in[1];
    const float* wout = (const float*)d_in[2];
    // block_mask (d_in[3]) is tril(ones) == causal; handled analytically.

    _Float16* ws = (_Float16*)d_ws;
    _Float16* xh = ws;                                    // L*D
    _Float16* wqkvh = xh + (size_t)L * D;                 // 3*D*D
    _Float16* wouth = wqkvh + (size_t)3 * D * D;          // D*D
    _Float16* qkh = wouth + (size_t)D * D;                // 2*NH*L*HD
    _Float16* vth = qkh + (size_t)2 * NH * L * HD;        // NH*HD*L
    _Float16* aoh = vth + (size_t)NH * HD * L;            // L*D
    _Float16* Oab = aoh + (size_t)L * D;                  // 2*L*D fp16 partials
    float* Lab = (float*)(Oab + (size_t)2 * L * D);       // 2*NH*L f32
    int* cnt = (int*)(Lab + (size_t)2 * NH * L);          // work-queue counter

    (void)hipMemsetAsync(cnt, 0, 256, stream);

    cvt3_kernel<<<2048, 256, 0, stream>>>(x, wqkv, wout, xh, wqkvh, wouth,
                                          L * D / 4, 3 * D * D / 4, D * D / 4);

    gemm_nt<<<dim3(L / 128, 3 * D / 128), 256, 0, stream>>>(
        xh, wqkvh, qkh, vth, L, 3 * D, D);

    norm_rope<<<2 * NH * L / 4, 256, 0, stream>>>(qkh);

    attn_kernel<<<768, 256, 0, stream>>>(qkh, vth, Oab, Lab, cnt);

    normalize_o<<<L * D / 8 / 256, 256, 0, stream>>>(Oab, Lab, aoh);

    gemm_out<<<dim3(L / 64, D / 128), 256, 0, stream>>>(
        aoh, wouth, (float*)d_out, L, D, D);
}

// Round 18
// 192.502 us; speedup vs baseline: 3.2047x; 1.0069x over previous
//
#include <hip/hip_runtime.h>

#define L 2048
#define D 2048
#define NH 16
#define HD 128

typedef __attribute__((ext_vector_type(8))) _Float16 half8;
typedef __attribute__((ext_vector_type(4))) float f32x4;

__device__ __forceinline__ void gload_lds16(const void* g, void* l) {
    __builtin_amdgcn_global_load_lds(
        (const __attribute__((address_space(1))) uint32_t*)g,
        (__attribute__((address_space(3))) uint32_t*)l, 16, 0, 0);
}

// pack two f32 -> fp16x2 (RTZ), return as u32
__device__ __forceinline__ unsigned pkrtz_u32(float a, float b) {
    union { __fp16 __attribute__((ext_vector_type(2))) h; unsigned u; } c;
    c.h = __builtin_amdgcn_cvt_pkrtz(a, b);
    return c.u;
}

// ---------------- fused f32 -> fp16 convert of x, W_qkv, W_out ----------------
__global__ void cvt3_kernel(const float* __restrict__ a, const float* __restrict__ b,
                            const float* __restrict__ c, _Float16* __restrict__ oa,
                            _Float16* __restrict__ ob, _Float16* __restrict__ oc,
                            int na, int nb, int nc) {
    int idx = blockIdx.x * blockDim.x + threadIdx.x;
    int stride = gridDim.x * blockDim.x;
    int ntot = na + nb + nc;
    for (int i = idx; i < ntot; i += stride) {
        const float* src; _Float16* dst; int j;
        if (i < na)            { src = a; dst = oa; j = i; }
        else if (i < na + nb)  { src = b; dst = ob; j = i - na; }
        else                   { src = c; dst = oc; j = i - na - nb; }
        float4 v = reinterpret_cast<const float4*>(src)[j];
        union { _Float16 h[4]; uint2 u; } pk;
        pk.h[0] = (_Float16)v.x; pk.h[1] = (_Float16)v.y;
        pk.h[2] = (_Float16)v.z; pk.h[3] = (_Float16)v.w;
        reinterpret_cast<uint2*>(dst)[j] = pk.u;
    }
}

// ---------------- NT GEMM (QKV): C[M][N] = A[M][K] * B[N][K]^T ----------------
// r13-exact proven structure (73us/706TF): 2-buffer, stage(t+1) -> compute(t)
// -> vmcnt(0)+__syncthreads drain. No T1 swizzle (r16: it cost 10%).
// 128x128 block tile, 4 waves 2x2, 4x4 16x16x32 fragments per wave, BK=32.
// Epilogue scatters qkv: q -> qk[0][h][l][d] linear;
//   k -> qk[1][h][l][d^((l&7)<<3)]  (XOR-swizzled for attn K staging);
//   v -> vt[h][d][l^((d&7)<<3)]     (XOR-swizzled for attn V staging).
__global__ __launch_bounds__(256) void gemm_nt(
    const _Float16* __restrict__ A, const _Float16* __restrict__ B,
    _Float16* __restrict__ qk, _Float16* __restrict__ vt,
    int M, int N, int K)
{
    __shared__ __align__(16) _Float16 Asm[2][128 * 32];   // 2 x 8 KB
    __shared__ __align__(16) _Float16 Bsm[2][128 * 32];   // 2 x 8 KB
    int tid = threadIdx.x;
    int wid = tid >> 6;
    int lane = tid & 63;
    int wr = wid >> 1, wc = wid & 1;
    int m0 = blockIdx.x * 128;
    int n0 = blockIdx.y * 128;
    int lr = lane & 15;   // row/col within 16
    int lg = lane >> 4;   // group 0..3

    // staging source: thread tid covers tile rows {tid>>2, 64+(tid>>2)}, byte col (tid&3)*16
    const char* Asrc = (const char*)(A + (size_t)(m0 + (tid >> 2)) * K) + (tid & 3) * 16;
    const char* Bsrc = (const char*)(B + (size_t)(n0 + (tid >> 2)) * K) + (tid & 3) * 16;
    size_t rowskip = (size_t)64 * K * 2;   // 64 rows of source, bytes

    auto stage = [&](int k0, int b) {
        const char* as = Asrc + (size_t)k0 * 2;
        const char* bs = Bsrc + (size_t)k0 * 2;
        char* ad = (char*)&Asm[b][0] + wid * 1024;   // + lane*16 by hardware
        char* bd = (char*)&Bsm[b][0] + wid * 1024;
        gload_lds16(as, ad);
        gload_lds16(as + rowskip, ad + 4096);
        gload_lds16(bs, bd);
        gload_lds16(bs + rowskip, bd + 4096);
    };

    f32x4 acc[4][4];
#pragma unroll
    for (int i = 0; i < 4; i++)
#pragma unroll
        for (int j = 0; j < 4; j++)
            acc[i][j] = (f32x4){0.f, 0.f, 0.f, 0.f};

    int NT = K / 32;
    stage(0, 0);
    asm volatile("s_waitcnt vmcnt(0)" ::: "memory");
    __syncthreads();

    for (int t = 0; t < NT; t++) {
        int cur = t & 1;
        if (t + 1 < NT) stage((t + 1) * 32, cur ^ 1);

        const char* ab = (const char*)&Asm[cur][0] + (wr * 64 + lr) * 64 + lg * 16;
        const char* bb = (const char*)&Bsm[cur][0] + (wc * 64 + lr) * 64 + lg * 16;
        half8 a[4], b[4];
#pragma unroll
        for (int i = 0; i < 4; i++) a[i] = *(const half8*)(ab + i * 1024);
#pragma unroll
        for (int j = 0; j < 4; j++) b[j] = *(const half8*)(bb + j * 1024);
#pragma unroll
        for (int i = 0; i < 4; i++)
#pragma unroll
            for (int j = 0; j < 4; j++)
                acc[i][j] = __builtin_amdgcn_mfma_f32_16x16x32_f16(a[i], b[j], acc[i][j], 0, 0, 0);

        asm volatile("s_waitcnt vmcnt(0)" ::: "memory");
        __syncthreads();
    }

#pragma unroll
    for (int i = 0; i < 4; i++) {
#pragma unroll
        for (int j = 0; j < 4; j++) {
#pragma unroll
            for (int r = 0; r < 4; r++) {
                int row = m0 + wr * 64 + i * 16 + lg * 4 + r;  // C layout: row=(lane>>4)*4+reg
                int col = n0 + wc * 64 + j * 16 + lr;          //           col=lane&15
                float v = acc[i][j][r];
                int t = col >> 11;
                int w2 = col & 2047;
                int h = w2 >> 7, d = w2 & 127;
                if (t == 0) {
                    qk[(((size_t)h) * L + row) * HD + d] = (_Float16)v;
                } else if (t == 1) {
                    int dsw = d ^ ((row & 7) << 3);   // pre-swizzle for attn K staging
                    qk[(((size_t)NH + h) * L + row) * HD + dsw] = (_Float16)v;
                } else {
                    int lsw = row ^ ((d & 7) << 3);   // pre-swizzle for attn V staging
                    vt[((size_t)h * HD + d) * L + lsw] = (_Float16)v;
                }
            }
        }
    }
}

// ---------------- output-projection GEMM: Cout[M][N] = A[M][K] * B[N][K]^T ----------------
// 64x128 block tile -> 512 blocks = 2 blocks/CU (r17: helped vs 1/CU).
__global__ __launch_bounds__(256) void gemm_out(
    const _Float16* __restrict__ A, const _Float16* __restrict__ B,
    float* __restrict__ Cout, int M, int N, int K)
{
    __shared__ __align__(16) _Float16 Asm[2][64 * 32];    // 2 x 4 KB
    __shared__ __align__(16) _Float16 Bsm[2][128 * 32];   // 2 x 8 KB
    int tid = threadIdx.x;
    int wid = tid >> 6;
    int lane = tid & 63;
    int m0 = blockIdx.x * 64;
    int n0 = blockIdx.y * 128;
    int lr = lane & 15;
    int lg = lane >> 4;

    const char* Asrc = (const char*)(A + (size_t)(m0 + (tid >> 2)) * K) + (tid & 3) * 16;
    const char* Bsrc = (const char*)(B + (size_t)(n0 + (tid >> 2)) * K) + (tid & 3) * 16;
    size_t rowskip = (size_t)64 * K * 2;

    auto stage = [&](int k0, int b) {
        const char* as = Asrc + (size_t)k0 * 2;
        const char* bs = Bsrc + (size_t)k0 * 2;
        char* ad = (char*)&Asm[b][0] + wid * 1024;   // + lane*16 by hardware
        char* bd = (char*)&Bsm[b][0] + wid * 1024;
        gload_lds16(as, ad);                 // A rows 0..63: LDS byte tid*16
        gload_lds16(bs, bd);                 // B rows 0..63
        gload_lds16(bs + rowskip, bd + 4096); // B rows 64..127
    };

    f32x4 acc[4][2];
#pragma unroll
    for (int i = 0; i < 4; i++)
#pragma unroll
        for (int j = 0; j < 2; j++)
            acc[i][j] = (f32x4){0.f, 0.f, 0.f, 0.f};

    int NT = K / 32;
    stage(0, 0);
    asm volatile("s_waitcnt vmcnt(0)" ::: "memory");
    __syncthreads();

    for (int t = 0; t < NT; t++) {
        int cur = t & 1;
        if (t + 1 < NT) stage((t + 1) * 32, cur ^ 1);

        const char* ab = (const char*)&Asm[cur][0] + lr * 64 + lg * 16;
        const char* bb = (const char*)&Bsm[cur][0] + (wid * 32 + lr) * 64 + lg * 16;
        half8 a[4], b[2];
#pragma unroll
        for (int i = 0; i < 4; i++) a[i] = *(const half8*)(ab + i * 1024);
#pragma unroll
        for (int j = 0; j < 2; j++) b[j] = *(const half8*)(bb + j * 1024);
#pragma unroll
        for (int i = 0; i < 4; i++)
#pragma unroll
            for (int j = 0; j < 2; j++)
                acc[i][j] = __builtin_amdgcn_mfma_f32_16x16x32_f16(a[i], b[j], acc[i][j], 0, 0, 0);

        asm volatile("s_waitcnt vmcnt(0)" ::: "memory");
        __syncthreads();
    }

#pragma unroll
    for (int i = 0; i < 4; i++) {
#pragma unroll
        for (int j = 0; j < 2; j++) {
#pragma unroll
            for (int r = 0; r < 4; r++) {
                int row = m0 + i * 16 + lg * 4 + r;
                int col = n0 + wid * 32 + j * 16 + lr;
                Cout[(size_t)row * N + col] = acc[i][j][r];
            }
        }
    }
}

// ---------------- fused RMSNorm + RoPE on q and k planes (in place) ----------------
__global__ void norm_rope(_Float16* __restrict__ qk) {
    int wid = threadIdx.x >> 6, lane = threadIdx.x & 63;
    int row = blockIdx.x * 4 + wid;      // 0 .. 2*NH*L-1
    int l = row & (L - 1);
    int th = row >> 11;                  // t*NH + h, 0..31
    _Float16* p = qk + ((size_t)th * L + l) * HD + lane * 2;
    float x0 = (float)p[0];
    float x1 = (float)p[1];
    float ss = x0 * x0 + x1 * x1;
#pragma unroll
    for (int off = 1; off < 64; off <<= 1) ss += __shfl_xor(ss, off);
    float r = rsqrtf(ss * (1.0f / 128.0f) + 1e-5f);
    float n0 = x0 * r, n1 = x1 * r;
    int i = (th >= NH) ? (lane ^ ((l & 7) << 2)) : lane;   // swizzle-aware pair index
    float freq = expf(-(float)(2 * i) * (1.0f / 128.0f) * logf(100000.0f));
    float ang = (float)l * freq;
    float s, c;
    sincosf(ang, &s, &c);
    p[0] = (_Float16)(n1 * c - n0 * s);
    p[1] = (_Float16)(n1 * s + n0 * c);
}

// ---------------- causal flash attention, v12: correct vmcnt ledger ----------------
// v11 BUG (r17 audit): stages were issued K(t+1) THEN V(t); vmcnt retires in
// ISSUE order, so the pre-PV vmcnt(4) waited the 4 OLDEST DMAs = the freshly
// issued K(t+1) (~full exposed latency EVERY tile) while V(t) -- the data PV
// actually reads -- was only covered by timing accident.
// v12: issue stage_v(t) FIRST, then stage_k(t+1). Now vmcnt(4) waits exactly
// V(t) (issued before QK -> hidden under 32 MFMAs) and K(t+1) stays genuinely
// in flight until next iteration's top vmcnt(0) (a full tile of slack).
// Strictly stronger correctness AND removes the per-tile naked stall.
// Everything else r13/r17-exact.
__global__ __launch_bounds__(256, 3) void attn_kernel(
    const _Float16* __restrict__ qk, const _Float16* __restrict__ vt,
    _Float16* __restrict__ Oab, float* __restrict__ Lab, int* __restrict__ cnt)
{
    __shared__ __align__(16) _Float16 Kt[2][64 * HD];     // 2 x 16 KB
    __shared__ __align__(16) _Float16 Vt[64 * HD];        // 16 KB, single-buffered
    __shared__ int sh_i;
    int wid = threadIdx.x >> 6, lane = threadIdx.x & 63;
    int lr = lane & 15, lg = lane >> 4;

    const float scale = 0.08838834764831845f;  // 1/sqrt(128)
    const float OFF = 4.0f;                    // static exp offset (absolute)

    for (;;) {
        __syncthreads();   // full drain between items (protects sh_i + Kt/Vt reuse)
        if (threadIdx.x == 0) sh_i = atomicAdd(cnt, 1);
        __syncthreads();
        int item = sh_i;
        if (item >= 1024) return;

        // decode big-first: qt descending; 32 items (16h x 2half) per qt
        int qt = 31 - (item >> 5);
        int h = (item >> 1) & 15;
        int half = item & 1;
        int n = qt + 1;
        int mid = (n + 1) >> 1;
        int t0 = half ? mid : 0;
        int t1 = half ? n : mid;
        int q0 = qt * 64 + wid * 16;
        int q_abs = q0 + lr;               // this lane's q-row (swapped layout)

        const _Float16* qn = qk + (size_t)h * L * HD;              // q plane
        const _Float16* kn = qk + ((size_t)(NH + h) * L) * HD;     // k plane (swizzled)
        const _Float16* vp = vt + (size_t)h * HD * L;              // v^T plane (swizzled)

        half8 qa[4];
#pragma unroll
        for (int kk = 0; kk < 4; kk++)
            qa[kk] = *reinterpret_cast<const half8*>(qn + (size_t)(q0 + lr) * HD + kk * 32 + lg * 8);

        f32x4 oacc[8];
#pragma unroll
        for (int jo = 0; jo < 8; jo++) oacc[jo] = (f32x4){0.f, 0.f, 0.f, 0.f};
        float lsum = 0.f;                  // per-lane scalar (q-row lr, this lane's kv slice)

        // per-wave QUARTER K stage: wave w copies kv rows 16w..16w+15 (4 KB, 4 DMAs)
        auto stage_k = [&](int t, int b) {
            const char* src = (const char*)(kn + (size_t)t * 64 * HD) + wid * 4096 + lane * 16;
            char* dst = (char*)&Kt[b][0] + wid * 4096;
#pragma unroll
            for (int i = 0; i < 4; i++)
                gload_lds16(src + i * 1024, dst + i * 1024);
        };
        // per-wave QUARTER V stage: tile [128 d][64 kv], 128B per d-row.
        auto stage_v = [&](int t) {
            const char* vpb = (const char*)vp + (size_t)t * 128;   // kv0*2 bytes
            char* dst = (char*)&Vt[0] + wid * 4096;
            int dbase = wid * 32 + (lane >> 3);
            int colb = (lane & 7) * 16;
#pragma unroll
            for (int i = 0; i < 4; i++)
                gload_lds16(vpb + (size_t)(dbase + i * 8) * (L * 2) + colb, dst + i * 1024);
        };

        if (t0 < t1) {
            stage_k(t0, 0);

            for (int t = t0; t < t1; t++) {
                int cur = (t - t0) & 1;
                int kv0 = t * 64;
                bool hasnext = (t + 1 < t1);

                // ---- own K(t) landed (issued a full tile ago; cheap wait) ----
                asm volatile("s_waitcnt vmcnt(0)" ::: "memory");
                __builtin_amdgcn_sched_barrier(0);

                // ---- raw barrier: all waves' K(t) landed; all waves done
                //      reading Vt (PV(t-1)) and Kt[cur^1] (QK(t-1)) ----
                __builtin_amdgcn_s_barrier();
                __builtin_amdgcn_sched_barrier(0);

                // ---- issue V(t) FIRST (oldest -> vmcnt(4) waits exactly it),
                //      then K(t+1) (youngest -> stays in flight a full tile) ----
                stage_v(t);
                if (hasnext) stage_k(t + 1, cur ^ 1);
                __builtin_amdgcn_sched_barrier(0);

                // ---- S^T = K Q^T from LDS (swapped operands) ----
                f32x4 sC[4];
#pragma unroll
                for (int jt = 0; jt < 4; jt++) sC[jt] = (f32x4){0.f, 0.f, 0.f, 0.f};
                const char* kb = (const char*)&Kt[cur][0];
                __builtin_amdgcn_s_setprio(1);
#pragma unroll
                for (int kk = 0; kk < 4; kk++) {
#pragma unroll
                    for (int jt = 0; jt < 4; jt++) {
                        half8 bk = *(const half8*)(kb + (jt * 16 + lr) * 256 +
                                                   ((kk * 64 + lg * 16) ^ ((lr & 7) << 4)));
                        sC[jt] = __builtin_amdgcn_mfma_f32_16x16x32_f16(bk, qa[kk], sC[jt], 0, 0, 0);
                    }
                }
                __builtin_amdgcn_s_setprio(0);

                // ---- lane-local softmax: pv = exp(s*scale - OFF), mask, pack ----
                bool diag = (t == qt);
                unsigned pkr[4][2];
#pragma unroll
                for (int jt = 0; jt < 4; jt++) {
                    float pv[4];
#pragma unroll
                    for (int r = 0; r < 4; r++) {
                        int kv = kv0 + jt * 16 + lg * 4 + r;
                        pv[r] = __expf(sC[jt][r] * scale - OFF);
                        if (diag && (kv > q_abs)) pv[r] = 0.f;
                        lsum += pv[r];
                    }
                    pkr[jt][0] = pkrtz_u32(pv[0], pv[1]);
                    pkr[jt][1] = pkrtz_u32(pv[2], pv[3]);
                }

                // ---- wait V(t) only (oldest 4); K(t+1) stays outstanding ----
                if (hasnext) asm volatile("s_waitcnt vmcnt(4)" ::: "memory");
                else         asm volatile("s_waitcnt vmcnt(0)" ::: "memory");
                __builtin_amdgcn_sched_barrier(0);

                // ---- O += P V (P A-fragments in-register; V from LDS) ----
                const char* vb = (const char*)&Vt[0];
                __builtin_amdgcn_s_setprio(1);
#pragma unroll
                for (int kk2 = 0; kk2 < 2; kk2++) {
                    union { unsigned u[4]; half8 h; } pa;
#pragma unroll
                    for (int c = 0; c < 4; c++) {
                        int src = lr + 16 * ((lg & 1) * 2 + (c >> 1));
                        unsigned va = __shfl(pkr[2 * kk2][c & 1], src);
                        unsigned vb2 = __shfl(pkr[2 * kk2 + 1][c & 1], src);
                        pa.u[c] = (lg < 2) ? va : vb2;
                    }
#pragma unroll
                    for (int jo = 0; jo < 8; jo++) {
                        int row = jo * 16 + lr;   // d index
                        half8 bv = *(const half8*)(vb + row * 128 +
                                                   ((kk2 * 64 + lg * 16) ^ ((row & 7) << 4)));
                        oacc[jo] = __builtin_amdgcn_mfma_f32_16x16x32_f16(pa.h, bv, oacc[jo], 0, 0, 0);
                    }
                }
                __builtin_amdgcn_s_setprio(0);
            }
        }

        // ---- lsum: reduce across the 4 lane-groups (kv slices) ----
        lsum += __shfl_xor(lsum, 16);
        lsum += __shfl_xor(lsum, 32);
        if (lane < 16)
            Lab[((size_t)half * NH + h) * L + q0 + lr] = lsum;

        // ---- write unnormalized partial O tile (fp16, owned exclusively) ----
        _Float16* ob = Oab + (size_t)half * L * D;
#pragma unroll
        for (int jo = 0; jo < 8; jo++) {
#pragma unroll
            for (int r = 0; r < 4; r++) {
                int row = q0 + lg * 4 + r;
                int col = h * HD + jo * 16 + lr;
                ob[(size_t)row * D + col] = (_Float16)oacc[jo][r];
            }
        }
    }
}

// ---------------- normalize: aoh = fp16((Oa+Ob) / (La+Lb)) ----------------
__global__ void normalize_o(const _Float16* __restrict__ Oab, const float* __restrict__ Lab,
                            _Float16* __restrict__ out) {
    int i8 = blockIdx.x * blockDim.x + threadIdx.x;   // over L*D/8
    int row = i8 >> 8;                                 // D/8 = 256
    int c8 = (i8 & 255) << 3;
    int h = c8 >> 7;
    half8 a = reinterpret_cast<const half8*>(Oab)[i8];
    half8 b = reinterpret_cast<const half8*>(Oab + (size_t)L * D)[i8];
    float la = Lab[(size_t)h * L + row];
    float lb = Lab[(size_t)(NH + h) * L + row];
    float inv = 1.0f / (la + lb);
    half8 o;
#pragma unroll
    for (int j = 0; j < 8; j++) o[j] = (_Float16)(((float)a[j] + (float)b[j]) * inv);
    reinterpret_cast<half8*>(out)[i8] = o;
}

extern "C" void kernel_launch(void* const* d_in, const int* in_sizes, int n_in,
                              void* d_out, int out_size, void* d_ws, size_t ws_size,
                              hipStream_t stream) {
    const float* x = (const float*)d_in[0];
    const float* wqkv = (const float*)d_in[1];
    const float* wout = (const float*)d_in[2];
    // block_mask (d_in[3]) is tril(ones) == causal; handled analytically.

    _Float16* ws = (_Float16*)d_ws;
    _Float16* xh = ws;                                    // L*D
    _Float16* wqkvh = xh + (size_t)L * D;                 // 3*D*D
    _Float16* wouth = wqkvh + (size_t)3 * D * D;          // D*D
    _Float16* qkh = wouth + (size_t)D * D;                // 2*NH*L*HD
    _Float16* vth = qkh + (size_t)2 * NH * L * HD;        // NH*HD*L
    _Float16* aoh = vth + (size_t)NH * HD * L;            // L*D
    _Float16* Oab = aoh + (size_t)L * D;                  // 2*L*D fp16 partials
    float* Lab = (float*)(Oab + (size_t)2 * L * D);       // 2*NH*L f32
    int* cnt = (int*)(Lab + (size_t)2 * NH * L);          // work-queue counter

    (void)hipMemsetAsync(cnt, 0, 256, stream);

    cvt3_kernel<<<2048, 256, 0, stream>>>(x, wqkv, wout, xh, wqkvh, wouth,
                                          L * D / 4, 3 * D * D / 4, D * D / 4);

    gemm_nt<<<dim3(L / 128, 3 * D / 128), 256, 0, stream>>>(
        xh, wqkvh, qkh, vth, L, 3 * D, D);

    norm_rope<<<2 * NH * L / 4, 256, 0, stream>>>(qkh);

    attn_kernel<<<768, 256, 0, stream>>>(qkh, vth, Oab, Lab, cnt);

    normalize_o<<<L * D / 8 / 256, 256, 0, stream>>>(Oab, Lab, aoh);

    gemm_out<<<dim3(L / 64, D / 128), 256, 0, stream>>>(
        aoh, wouth, (float*)d_out, L, D, D);
}